// Round 1
// baseline (126.057 us; speedup 1.0000x reference)
//
#include <hip/hip_runtime.h>
#include <hip/hip_bf16.h>

typedef __attribute__((ext_vector_type(8))) short short8;
typedef __attribute__((ext_vector_type(4))) float floatx4;

__device__ __forceinline__ short tobf16(float f) {
    unsigned u = __builtin_bit_cast(unsigned, f);
    u += 0x7fffu + ((u >> 16) & 1u);   // round-to-nearest-even
    return (short)(u >> 16);
}

// Kernel 1: P[v][h] = sum_d E[v][d] * W1[d][h]   (V x 300) @ (300 x 32)
// One wave per 16-row M-tile. W1 lives entirely in registers as MFMA B-frags.
// MFMA 16x16x32 bf16, K padded 300 -> 320 (last step masked).
__global__ __launch_bounds__(256) void project_kernel(
        const float* __restrict__ E, const float* __restrict__ W1,
        float* __restrict__ P, int V) {
    int wid  = (blockIdx.x * blockDim.x + threadIdx.x) >> 6;
    int lane = threadIdx.x & 63;
    int tiles = V >> 4;
    if (wid >= tiles) return;
    int v0   = wid << 4;
    int m    = lane & 15;      // A row / C col / B col-within-tile
    int quad = lane >> 4;      // 0..3

    // B-frags: B[k][n] with k = s*32 + quad*8 + j, n = t*16 + m
    short8 bfrag[10][2];
#pragma unroll
    for (int s = 0; s < 10; ++s) {
#pragma unroll
        for (int t = 0; t < 2; ++t) {
            short8 f;
#pragma unroll
            for (int j = 0; j < 8; ++j) {
                int k = s * 32 + quad * 8 + j;
                int n = t * 16 + m;
                float w = (k < 300) ? W1[k * 32 + n] : 0.f;
                f[j] = tobf16(w);
            }
            bfrag[s][t] = f;
        }
    }

    const float* arow = E + (size_t)(v0 + m) * 300;
    floatx4 acc0 = {0.f, 0.f, 0.f, 0.f};
    floatx4 acc1 = {0.f, 0.f, 0.f, 0.f};

#pragma unroll
    for (int s = 0; s < 9; ++s) {   // k0 = 0..256, all columns < 300
        floatx4 f0 = *(const floatx4*)(arow + s * 32 + quad * 8);
        floatx4 f1 = *(const floatx4*)(arow + s * 32 + quad * 8 + 4);
        short8 a;
        a[0] = tobf16(f0[0]); a[1] = tobf16(f0[1]);
        a[2] = tobf16(f0[2]); a[3] = tobf16(f0[3]);
        a[4] = tobf16(f1[0]); a[5] = tobf16(f1[1]);
        a[6] = tobf16(f1[2]); a[7] = tobf16(f1[3]);
        acc0 = __builtin_amdgcn_mfma_f32_16x16x32_bf16(a, bfrag[s][0], acc0, 0, 0, 0);
        acc1 = __builtin_amdgcn_mfma_f32_16x16x32_bf16(a, bfrag[s][1], acc1, 0, 0, 0);
    }
    {   // s = 9: k0 = 288, columns 288..303, mask >= 300
        short8 a;
#pragma unroll
        for (int j = 0; j < 8; ++j) {
            int c = 288 + quad * 8 + j;
            a[j] = (c < 300) ? tobf16(arow[c]) : (short)0;
        }
        acc0 = __builtin_amdgcn_mfma_f32_16x16x32_bf16(a, bfrag[9][0], acc0, 0, 0, 0);
        acc1 = __builtin_amdgcn_mfma_f32_16x16x32_bf16(a, bfrag[9][1], acc1, 0, 0, 0);
    }

    // C/D layout (verified): col = lane&15, row = quad*4 + reg
#pragma unroll
    for (int r = 0; r < 4; ++r) {
        int row = quad * 4 + r;
        P[(size_t)(v0 + row) * 32 + m]      = acc0[r];
        P[(size_t)(v0 + row) * 32 + 16 + m] = acc1[r];
    }
}

// Kernel 2: per batch row b: acc[h] = sum_l P[x[b,l]][h]; then MLP.
// Block = 256 threads = 4 waves, each wave handles L/4 tokens.
__global__ __launch_bounds__(256) void pool_mlp_kernel(
        const int* __restrict__ x, const int* __restrict__ lengths,
        const float* __restrict__ P, const float* __restrict__ b1,
        const float* __restrict__ W2, const float* __restrict__ b2,
        float* __restrict__ out, int L, int C) {
    __shared__ int   xs[512];
    __shared__ float red[4][32];
    int b    = blockIdx.x;
    int w    = threadIdx.x >> 6;
    int lane = threadIdx.x & 63;
    int h    = lane & 31;

    const int* xrow = x + (size_t)b * L;
    for (int i = threadIdx.x; i < L; i += 256) xs[i] = xrow[i];
    __syncthreads();

    int Lw    = (L + 3) >> 2;
    int start = w * Lw;
    int end   = min(start + Lw, L);

    float acc = 0.f;
    // lanes 0-31 take token t, lanes 32-63 take token t+1 (contiguous 128B rows)
    for (int t = start; t < end; t += 2) {
        int tt  = t + (lane >> 5);
        int idx = (tt < end) ? xs[tt] : -1;
        if (idx >= 0) acc += P[(size_t)idx * 32 + h];
    }
    acc += __shfl_xor(acc, 32, 64);        // combine both halves (same h)
    if (lane < 32) red[w][h] = acc;
    __syncthreads();

    if (threadIdx.x < 32) {
        float s    = red[0][h] + red[1][h] + red[2][h] + red[3][h];
        float lenf = (float)lengths[b];
        float hv   = fmaxf(s / lenf + b1[h], 0.f);
        for (int c = 0; c < C; ++c) {
            float p = hv * W2[h * C + c];
            p += __shfl_xor(p, 16, 64);
            p += __shfl_xor(p, 8, 64);
            p += __shfl_xor(p, 4, 64);
            p += __shfl_xor(p, 2, 64);
            p += __shfl_xor(p, 1, 64);
            if (threadIdx.x == 0) out[(size_t)b * C + c] = p + b2[c];
        }
    }
}

// Generic fallback (unexpected shapes or too-small workspace): correct, not fast.
__global__ void naive_dnn(const int* __restrict__ x, const int* __restrict__ len,
                          const float* __restrict__ emb, const float* __restrict__ W1,
                          const float* __restrict__ b1, const float* __restrict__ W2,
                          const float* __restrict__ b2, float* __restrict__ out,
                          int L, int V, int D, int H, int C) {
    __shared__ float srep[2048];
    __shared__ float sh[256];
    int b = blockIdx.x;
    float lenf = (float)len[b];
    for (int d = threadIdx.x; d < D; d += blockDim.x) {
        float acc = 0.f;
        for (int l = 0; l < L; ++l) {
            int idx = x[(size_t)b * L + l];
            acc += emb[(size_t)idx * D + d];
        }
        srep[d] = acc / lenf;
    }
    __syncthreads();
    for (int hh = threadIdx.x; hh < H; hh += blockDim.x) {
        float a = b1[hh];
        for (int d = 0; d < D; ++d) a += srep[d] * W1[(size_t)d * H + hh];
        sh[hh] = fmaxf(a, 0.f);
    }
    __syncthreads();
    for (int c = threadIdx.x; c < C; c += blockDim.x) {
        float a = b2[c];
        for (int hh = 0; hh < H; ++hh) a += sh[hh] * W2[hh * C + c];
        out[(size_t)b * C + c] = a;
    }
}

extern "C" void kernel_launch(void* const* d_in, const int* in_sizes, int n_in,
                              void* d_out, int out_size, void* d_ws, size_t ws_size,
                              hipStream_t stream) {
    const int*   x       = (const int*)d_in[0];
    const int*   lengths = (const int*)d_in[1];
    const float* emb     = (const float*)d_in[2];
    const float* W1      = (const float*)d_in[3];
    const float* b1      = (const float*)d_in[4];
    const float* W2      = (const float*)d_in[5];
    const float* b2      = (const float*)d_in[6];
    float* out = (float*)d_out;

    int B = in_sizes[1];
    int L = in_sizes[0] / B;
    int H = in_sizes[4];
    int C = in_sizes[6];
    int D = in_sizes[3] / H;
    int V = in_sizes[2] / D;

    bool fast = (D == 300) && (H == 32) && ((V & 15) == 0) && (L <= 512) &&
                (ws_size >= (size_t)V * H * sizeof(float));
    if (fast) {
        float* P = (float*)d_ws;
        int tiles  = V >> 4;                       // 3125
        int blocks = (tiles + 3) / 4;              // 4 waves/block
        project_kernel<<<blocks, 256, 0, stream>>>(emb, W1, P, V);
        pool_mlp_kernel<<<B, 256, 0, stream>>>(x, lengths, P, b1, W2, b2, out, L, C);
    } else {
        naive_dnn<<<B, 256, 0, stream>>>(x, lengths, emb, W1, b1, b2 ? W2 : W2, b2, out,
                                         L, V, D, H, C);
    }
}